// Round 3
// baseline (299.183 us; speedup 1.0000x reference)
//
#include <hip/hip_runtime.h>
#include <hip/hip_bf16.h>

// QHNet block-linear layer: out[b] (40x40), all GEMMs vs L2-resident bf16
// weights with scales folded. R3: swapped MFMA operands (A=W, B=x) so each
// lane holds 4 consecutive output-n for one batch row -> direct aligned
// global_store_dwordx4 from accumulators, no output LDS stage at all.
// (R2's LDS epilogue: ~800 half-exec ds_writes/block + 3 barriers = ~100us.)

typedef short bf16x8 __attribute__((ext_vector_type(8)));
typedef float f32x4 __attribute__((ext_vector_type(4)));

static __device__ __forceinline__ unsigned short f2bf(float f) {
    __hip_bfloat16 h = __float2bfloat16(f);
    union { __hip_bfloat16 h; unsigned short u; } cvt; cvt.h = h;
    return cvt.u;
}

// ---- weight prep: transpose to W[n][k] bf16 with scales folded -------------
__global__ void prep_w(const float* __restrict__ w,
                       unsigned short* __restrict__ w0t,
                       unsigned short* __restrict__ w1t) {
    int idx = blockIdx.x * 256 + threadIdx.x;   // 240*256 == 61440 exactly
    const float S000 = 1.0f / 128.0f;
    const float S011 = 1.0f / (128.0f * 1.7320508075688772f);
    const float S1X  = 1.0f / (64.0f * 1.7320508075688772f);
    const float S111 = 1.0f / (64.0f * 2.449489742783178f);
    if (idx < 320 * 128) {
        int n = idx >> 7, k = idx & 127;
        float v;
        if (n < 256) v = w[k * 256 + n] * S000;                 // w000[k][uv]
        else         v = w[32768 + k * 64 + (n - 256)] * S011;  // w011[k][uv]
        w0t[idx] = f2bf(v);
    } else {
        int i2 = idx - 320 * 128;
        int n = i2 >> 6, k = i2 & 63;
        float v;
        if (n < 128)      v = w[40960 + k * 128 + n] * S1X;           // w101
        else if (n < 256) v = w[49152 + k * 128 + (n - 128)] * S1X;   // w110
        else              v = w[57344 + k * 64  + (n - 256)] * S111;  // w111
        w1t[i2] = f2bf(v);
    }
}

// ---- main fused kernel -----------------------------------------------------
// 256 threads = 4 waves; batch tile = 16 rows; wave wv owns an n-slice.
// Swapped MFMA: D[n][batch]; lane holds n = n0 + grp*4 + {0..3}, batch = cn.
__global__ __launch_bounds__(256) void qhnet_main(
    const float* __restrict__ x_in,
    const unsigned short* __restrict__ w0t,
    const unsigned short* __restrict__ w1t,
    float* __restrict__ out)
{
    __shared__ unsigned short x0L[16 * 128];      // [row][k ^ ((row&7)<<3)]
    __shared__ unsigned short x1L[3][16 * 64];    // [comp][row][w ^ ((row&7)<<3)]

    const int tid = threadIdx.x;
    const int b0 = blockIdx.x * 16;

    // --- stage x tile -> LDS as bf16 (coalesced float4 reads) ---
    const float4* xrow = reinterpret_cast<const float4*>(x_in + (size_t)b0 * 320);
    for (int p = tid; p < 16 * 80; p += 256) {
        int row = p / 80;
        int c4 = p - row * 80;
        float4 v = xrow[p];
        int sw = (row & 7) << 3;
        int col = c4 * 4;
        if (col < 128) {
            int k = col ^ sw;   // XOR-swizzle keeps 4-aligned contiguity
            ushort4 u;
            u.x = f2bf(v.x); u.y = f2bf(v.y); u.z = f2bf(v.z); u.w = f2bf(v.w);
            *reinterpret_cast<ushort4*>(&x0L[row * 128 + k]) = u;
        } else {
            float vv[4] = {v.x, v.y, v.z, v.w};
            #pragma unroll
            for (int e = 0; e < 4; ++e) {
                int f = col - 128 + e;
                int wi = f / 3, cm = f - wi * 3;
                x1L[cm][row * 64 + (wi ^ sw)] = f2bf(vv[e]);
            }
        }
    }
    __syncthreads();

    const int lane = tid & 63;
    const int wv = tid >> 6;        // wave id 0..3 -> n-slice
    const int cn = lane & 15;       // batch row in tile (B-frag col; A-frag row=n)
    const int grp = lane >> 4;      // k-group 0..3
    const int swf = (cn & 7) << 3;

    // --- x fragments from LDS (B operand: col=batch=cn, k=grp*8) ---
    bf16x8 a0[4], a1[3][2];
    #pragma unroll
    for (int ks = 0; ks < 4; ++ks)
        a0[ks] = *reinterpret_cast<const bf16x8*>(
            &x0L[cn * 128 + ((ks * 32 + grp * 8) ^ swf)]);
    #pragma unroll
    for (int c = 0; c < 3; ++c)
        #pragma unroll
        for (int ks = 0; ks < 2; ++ks)
            a1[c][ks] = *reinterpret_cast<const bf16x8*>(
                &x1L[c][cn * 64 + ((ks * 32 + grp * 8) ^ swf)]);

    f32x4 acc0[5] = {};
    f32x4 acc1[3][5] = {};

    const int c0base[5] = {wv * 64, wv * 64 + 16, wv * 64 + 32, wv * 64 + 48,
                           256 + wv * 16};
    const int c1base[5] = {wv * 32, wv * 32 + 16, 128 + wv * 32,
                           128 + wv * 32 + 16, 256 + wv * 16};

    // --- C0^T = W0^T @ X0^T (K=128): A = weight frag (row n), B = x frag ---
    #pragma unroll
    for (int t = 0; t < 5; ++t) {
        const unsigned short* wp = w0t + (c0base[t] + cn) * 128 + grp * 8;
        #pragma unroll
        for (int ks = 0; ks < 4; ++ks) {
            bf16x8 b = *reinterpret_cast<const bf16x8*>(wp + ks * 32);
            acc0[t] = __builtin_amdgcn_mfma_f32_16x16x32_bf16(b, a0[ks], acc0[t], 0, 0, 0);
        }
    }
    // --- C1k^T (K=64), weight frag shared across the 3 components ---
    #pragma unroll
    for (int t = 0; t < 5; ++t) {
        const unsigned short* wp = w1t + (c1base[t] + cn) * 64 + grp * 8;
        #pragma unroll
        for (int ks = 0; ks < 2; ++ks) {
            bf16x8 b = *reinterpret_cast<const bf16x8*>(wp + ks * 32);
            #pragma unroll
            for (int c = 0; c < 3; ++c)
                acc1[c][t] = __builtin_amdgcn_mfma_f32_16x16x32_bf16(b, a1[c][ks], acc1[c][t], 0, 0, 0);
        }
    }

    // --- epilogue: direct aligned dwordx4 stores from accumulators ---
    // Lane owns batch row (b0+cn); n = base + grp*4 + reg (4 consecutive).
    float* orow = out + (size_t)(b0 + cn) * 1600;
    const int g2 = grp >> 1, g1 = grp & 1;

    #pragma unroll
    for (int t = 0; t < 4; ++t) {               // blk00: row u=wv*4+t, cols grp*4+
        *reinterpret_cast<float4*>(&orow[(wv * 4 + t) * 40 + grp * 4]) =
            *reinterpret_cast<const float4*>(&acc0[t]);
    }

    #pragma unroll
    for (int t = 0; t < 2; ++t) {               // blk01: 12 consecutive floats
        int u01 = 4 * wv + 2 * t + g2;          // n01 = u01*8 + v, v = g1*4+reg
        float* o = &orow[u01 * 40 + 16 + 12 * g1];
        float4 q0 = {acc1[0][t][0], acc1[1][t][0], acc1[2][t][0], acc1[0][t][1]};
        float4 q1 = {acc1[1][t][1], acc1[2][t][1], acc1[0][t][2], acc1[1][t][2]};
        float4 q2 = {acc1[2][t][2], acc1[0][t][3], acc1[1][t][3], acc1[2][t][3]};
        *reinterpret_cast<float4*>(o)     = q0;
        *reinterpret_cast<float4*>(o + 4) = q1;
        *reinterpret_cast<float4*>(o + 8) = q2;
    }

    #pragma unroll
    for (int t = 0; t < 2; ++t) {               // blk10: row 16+3u+c, cols grp*4+
        int u = 2 * wv + t;
        #pragma unroll
        for (int c = 0; c < 3; ++c)
            *reinterpret_cast<float4*>(&orow[(16 + 3 * u + c) * 40 + grp * 4]) =
                *reinterpret_cast<const float4*>(&acc1[c][t + 2]);
    }

    {                                           // blk11: diag r011 + eps*t_k
        int u = 2 * wv + g2;                    // uv = u*8 + v, v = g1*4+reg
        float* ob = &orow[(16 + 3 * u) * 40 + 16 + 12 * g1];
        f32x4 d = acc0[4];
        f32x4 t0 = acc1[0][4], t1 = acc1[1][4], t2 = acc1[2][4];
        // row i=0: per reg triple (d, t2, -t1)
        float4 q00 = {d[0], t2[0], -t1[0], d[1]};
        float4 q01 = {t2[1], -t1[1], d[2], t2[2]};
        float4 q02 = {-t1[2], d[3], t2[3], -t1[3]};
        // row i=1: (-t2, d, t0)
        float4 q10 = {-t2[0], d[0], t0[0], -t2[1]};
        float4 q11 = {d[1], t0[1], -t2[2], d[2]};
        float4 q12 = {t0[2], -t2[3], d[3], t0[3]};
        // row i=2: (t1, -t0, d)
        float4 q20 = {t1[0], -t0[0], d[0], t1[1]};
        float4 q21 = {-t0[1], d[1], t1[2], -t0[2]};
        float4 q22 = {d[2], t1[3], -t0[3], d[3]};
        *reinterpret_cast<float4*>(ob)          = q00;
        *reinterpret_cast<float4*>(ob + 4)      = q01;
        *reinterpret_cast<float4*>(ob + 8)      = q02;
        *reinterpret_cast<float4*>(ob + 40)     = q10;
        *reinterpret_cast<float4*>(ob + 44)     = q11;
        *reinterpret_cast<float4*>(ob + 48)     = q12;
        *reinterpret_cast<float4*>(ob + 80)     = q20;
        *reinterpret_cast<float4*>(ob + 84)     = q21;
        *reinterpret_cast<float4*>(ob + 88)     = q22;
    }
}

extern "C" void kernel_launch(void* const* d_in, const int* in_sizes, int n_in,
                              void* d_out, int out_size, void* d_ws, size_t ws_size,
                              hipStream_t stream) {
    const float* x_in = (const float*)d_in[0];
    const float* weights = (const float*)d_in[1];
    float* out = (float*)d_out;
    unsigned short* w0t = (unsigned short*)d_ws;            // 320*128 bf16
    unsigned short* w1t = w0t + 320 * 128;                  // 320*64  bf16
    int B = in_sizes[0] / 320;                              // 100000

    prep_w<<<240, 256, 0, stream>>>(weights, w0t, w1t);
    qhnet_main<<<B / 16, 256, 0, stream>>>(x_in, w0t, w1t, out);
}

// Round 4
// 279.173 us; speedup vs baseline: 1.0717x; 1.0717x over previous
//
#include <hip/hip_runtime.h>
#include <hip/hip_bf16.h>

// QHNet block-linear layer. R4: swapped-operand MFMA (lane holds 4
// consecutive n for one batch row) + quad-granular LDS output staging:
// 25 ds_write_b128 per thread (XOR-swizzled, conflict-free) replaces R2's
// 100 scattered ds_write_b32; 4-row output tile (25.6KB LDS) +
// __launch_bounds__(256,4) targets 16 waves/CU (R2: 12).
// R3 lesson: direct global quad stores = 16 misaligned 64B segments/instr
// -> transaction-bound (299us). Coalesced LDS->global copy is mandatory.

typedef short bf16x8 __attribute__((ext_vector_type(8)));
typedef float f32x4 __attribute__((ext_vector_type(4)));

static __device__ __forceinline__ unsigned short f2bf(float f) {
    __hip_bfloat16 h = __float2bfloat16(f);
    union { __hip_bfloat16 h; unsigned short u; } cvt; cvt.h = h;
    return cvt.u;
}

// ---- weight prep: transpose to W[n][k] bf16 with scales folded -------------
__global__ void prep_w(const float* __restrict__ w,
                       unsigned short* __restrict__ w0t,
                       unsigned short* __restrict__ w1t) {
    int idx = blockIdx.x * 256 + threadIdx.x;   // 240*256 == 61440 exactly
    const float S000 = 1.0f / 128.0f;
    const float S011 = 1.0f / (128.0f * 1.7320508075688772f);
    const float S1X  = 1.0f / (64.0f * 1.7320508075688772f);
    const float S111 = 1.0f / (64.0f * 2.449489742783178f);
    if (idx < 320 * 128) {
        int n = idx >> 7, k = idx & 127;
        float v;
        if (n < 256) v = w[k * 256 + n] * S000;                 // w000[k][uv]
        else         v = w[32768 + k * 64 + (n - 256)] * S011;  // w011[k][uv]
        w0t[idx] = f2bf(v);
    } else {
        int i2 = idx - 320 * 128;
        int n = i2 >> 6, k = i2 & 63;
        float v;
        if (n < 128)      v = w[40960 + k * 128 + n] * S1X;           // w101
        else if (n < 256) v = w[49152 + k * 128 + (n - 128)] * S1X;   // w110
        else              v = w[57344 + k * 64  + (n - 256)] * S111;  // w111
        w1t[i2] = f2bf(v);
    }
}

// ---- main fused kernel -----------------------------------------------------
// 256 threads = 4 waves; batch tile = 16 rows; wave wv owns an n-quarter.
// Swapped MFMA: D[n][batch]; lane holds n = base + grp*4 + {0..3}, batch = cn.
__global__ __launch_bounds__(256, 4) void qhnet_main(
    const float* __restrict__ x_in,
    const unsigned short* __restrict__ w0t,
    const unsigned short* __restrict__ w1t,
    float* __restrict__ out)
{
    // 25600 B: aliased as bf16 x-staging (10240 B), then 4-row f32 out tile.
    __shared__ __attribute__((aligned(16))) float smemf[4 * 1600];
    unsigned short* x0L = reinterpret_cast<unsigned short*>(smemf); // [16][128]
    unsigned short* x1L = x0L + 16 * 128;                           // [3][16][64]
    float4* smemq = reinterpret_cast<float4*>(smemf);               // [4][400]

    const int tid = threadIdx.x;
    const int b0 = blockIdx.x * 16;

    // --- stage x tile -> LDS as bf16 (coalesced float4 reads) ---
    const float4* xrow = reinterpret_cast<const float4*>(x_in + (size_t)b0 * 320);
    for (int p = tid; p < 16 * 80; p += 256) {
        int row = p / 80;
        int c4 = p - row * 80;
        float4 v = xrow[p];
        int sw = (row & 7) << 3;
        int col = c4 * 4;
        if (col < 128) {
            int k = col ^ sw;   // XOR-swizzle keeps 4-aligned contiguity
            ushort4 u;
            u.x = f2bf(v.x); u.y = f2bf(v.y); u.z = f2bf(v.z); u.w = f2bf(v.w);
            *reinterpret_cast<ushort4*>(&x0L[row * 128 + k]) = u;
        } else {
            float vv[4] = {v.x, v.y, v.z, v.w};
            #pragma unroll
            for (int e = 0; e < 4; ++e) {
                int f = col - 128 + e;
                int wi = f / 3, cm = f - wi * 3;
                x1L[cm * 1024 + row * 64 + (wi ^ sw)] = f2bf(vv[e]);
            }
        }
    }
    __syncthreads();

    const int lane = tid & 63;
    const int wv = tid >> 6;        // wave id 0..3 -> n-quarter
    const int cn = lane & 15;       // batch row in tile
    const int grp = lane >> 4;      // k-group / reg-quad select
    const int swf = (cn & 7) << 3;

    f32x4 acc0[5] = {};
    f32x4 acc1[3][5] = {};

    const int c0base[5] = {wv * 64, wv * 64 + 16, wv * 64 + 32, wv * 64 + 48,
                           256 + wv * 16};
    const int c1base[5] = {wv * 32, wv * 32 + 16, 128 + wv * 32,
                           128 + wv * 32 + 16, 256 + wv * 16};

    // --- C0^T = W0 (A) x X0 (B), K=128 ---
    {
        bf16x8 a0[4];
        #pragma unroll
        for (int ks = 0; ks < 4; ++ks)
            a0[ks] = *reinterpret_cast<const bf16x8*>(
                &x0L[cn * 128 + ((ks * 32 + grp * 8) ^ swf)]);
        #pragma unroll
        for (int t = 0; t < 5; ++t) {
            const unsigned short* wp = w0t + (c0base[t] + cn) * 128 + grp * 8;
            #pragma unroll
            for (int ks = 0; ks < 4; ++ks) {
                bf16x8 b = *reinterpret_cast<const bf16x8*>(wp + ks * 32);
                acc0[t] = __builtin_amdgcn_mfma_f32_16x16x32_bf16(b, a0[ks], acc0[t], 0, 0, 0);
            }
        }
    }
    __builtin_amdgcn_sched_barrier(0);   // keep a1 lifetimes after C0 section

    // --- C1k^T, K=64, weight frag shared across the 3 components ---
    {
        bf16x8 a1[3][2];
        #pragma unroll
        for (int c = 0; c < 3; ++c)
            #pragma unroll
            for (int ks = 0; ks < 2; ++ks)
                a1[c][ks] = *reinterpret_cast<const bf16x8*>(
                    &x1L[c * 1024 + cn * 64 + ((ks * 32 + grp * 8) ^ swf)]);
        #pragma unroll
        for (int t = 0; t < 5; ++t) {
            const unsigned short* wp = w1t + (c1base[t] + cn) * 64 + grp * 8;
            #pragma unroll
            for (int ks = 0; ks < 2; ++ks) {
                bf16x8 b = *reinterpret_cast<const bf16x8*>(wp + ks * 32);
                #pragma unroll
                for (int c = 0; c < 3; ++c)
                    acc1[c][t] = __builtin_amdgcn_mfma_f32_16x16x32_bf16(b, a1[c][ks], acc1[c][t], 0, 0, 0);
            }
        }
    }

    // --- epilogue: 4 phases of 4 batch rows; quad scatter -> coalesced copy ---
    const int g2 = grp >> 1, g1 = grp & 1;
    const int tr = cn & 3;          // tile row when active
    const int kx = tr << 1;         // quad XOR key (2-way max conflicts)
    float4* rowq = smemq + tr * 400;

    #pragma unroll
    for (int h = 0; h < 4; ++h) {
        __syncthreads();    // h=0: frag reads done; else: prev copy done
        if ((cn >> 2) == h) {
            #pragma unroll
            for (int t = 0; t < 4; ++t) {               // blk00
                int q = (wv * 4 + t) * 10 + grp;
                rowq[q ^ kx] = *reinterpret_cast<const float4*>(&acc0[t]);
            }
            #pragma unroll
            for (int t = 0; t < 2; ++t) {               // blk01: 3 quads
                int u01 = 4 * wv + 2 * t + g2;
                int q0 = u01 * 10 + 4 + 3 * g1;
                float4 qa = {acc1[0][t][0], acc1[1][t][0], acc1[2][t][0], acc1[0][t][1]};
                float4 qb = {acc1[1][t][1], acc1[2][t][1], acc1[0][t][2], acc1[1][t][2]};
                float4 qc = {acc1[2][t][2], acc1[0][t][3], acc1[1][t][3], acc1[2][t][3]};
                rowq[q0 ^ kx]       = qa;
                rowq[(q0 + 1) ^ kx] = qb;
                rowq[(q0 + 2) ^ kx] = qc;
            }
            #pragma unroll
            for (int t = 0; t < 2; ++t) {               // blk10
                int rr = 16 + 3 * (2 * wv + t);
                #pragma unroll
                for (int c = 0; c < 3; ++c) {
                    int q = (rr + c) * 10 + grp;
                    rowq[q ^ kx] = *reinterpret_cast<const float4*>(&acc1[c][t + 2]);
                }
            }
            {                                           // blk11: 9 quads
                int rr = 16 + 3 * (2 * wv + g2);
                int cq = 4 + 3 * g1;
                f32x4 d = acc0[4];
                f32x4 t0 = acc1[0][4], t1 = acc1[1][4], t2 = acc1[2][4];
                float4 q00 = {d[0], t2[0], -t1[0], d[1]};
                float4 q01 = {t2[1], -t1[1], d[2], t2[2]};
                float4 q02 = {-t1[2], d[3], t2[3], -t1[3]};
                float4 q10 = {-t2[0], d[0], t0[0], -t2[1]};
                float4 q11 = {d[1], t0[1], -t2[2], d[2]};
                float4 q12 = {t0[2], -t2[3], d[3], t0[3]};
                float4 q20 = {t1[0], -t0[0], d[0], t1[1]};
                float4 q21 = {-t0[1], d[1], t1[2], -t0[2]};
                float4 q22 = {d[2], t1[3], -t0[3], d[3]};
                rowq[(rr * 10 + cq)            ^ kx] = q00;
                rowq[(rr * 10 + cq + 1)        ^ kx] = q01;
                rowq[(rr * 10 + cq + 2)        ^ kx] = q02;
                rowq[((rr + 1) * 10 + cq)      ^ kx] = q10;
                rowq[((rr + 1) * 10 + cq + 1)  ^ kx] = q11;
                rowq[((rr + 1) * 10 + cq + 2)  ^ kx] = q12;
                rowq[((rr + 2) * 10 + cq)      ^ kx] = q20;
                rowq[((rr + 2) * 10 + cq + 1)  ^ kx] = q21;
                rowq[((rr + 2) * 10 + cq + 2)  ^ kx] = q22;
            }
        }
        __syncthreads();
        // coalesced copy: wave w streams tile row w (1600 floats contiguous)
        {
            int row = tid >> 6;
            const float4* srcrow = smemq + row * 400;
            int kxr = row << 1;
            float* dst = out + (size_t)(b0 + h * 4 + row) * 1600;
            #pragma unroll
            for (int k = 0; k < 7; ++k) {
                int q = (tid & 63) + (k << 6);
                if (q < 400)
                    *reinterpret_cast<float4*>(dst + q * 4) = srcrow[q ^ kxr];
            }
        }
    }
}

extern "C" void kernel_launch(void* const* d_in, const int* in_sizes, int n_in,
                              void* d_out, int out_size, void* d_ws, size_t ws_size,
                              hipStream_t stream) {
    const float* x_in = (const float*)d_in[0];
    const float* weights = (const float*)d_in[1];
    float* out = (float*)d_out;
    unsigned short* w0t = (unsigned short*)d_ws;            // 320*128 bf16
    unsigned short* w1t = w0t + 320 * 128;                  // 320*64  bf16
    int B = in_sizes[0] / 320;                              // 100000

    prep_w<<<240, 256, 0, stream>>>(weights, w0t, w1t);
    qhnet_main<<<B / 16, 256, 0, stream>>>(x_in, w0t, w1t, out);
}

// Round 5
// 264.565 us; speedup vs baseline: 1.1308x; 1.0552x over previous
//
#include <hip/hip_runtime.h>
#include <hip/hip_bf16.h>

// QHNet block-linear layer. R5:
//  - prep_x pass converts x (f32) -> bf16 in MFMA-fragment layout
//    [b][ x0:128 | x1c0:64 | x1c1:64 | x1c2:64 ], so the main kernel loads
//    fragments straight from global (no LDS x-staging, no f2bf, -64MB reads).
//  - swapped-operand MFMA (lane holds 4 consecutive n of one batch row),
//    quad-granular LDS out-staging (25 ds_write_b128, XOR by row), R2's
//    proven 2-phase x 8-row structure, coalesced float4 copy-out.
//  - no forced launch_bounds min-waves (R4's (256,4) likely spilled).
// Fallback (ws too small for x-bf16): template path stages x in LDS as before.

typedef short bf16x8 __attribute__((ext_vector_type(8)));
typedef float f32x4 __attribute__((ext_vector_type(4)));

static __device__ __forceinline__ unsigned short f2bf(float f) {
    __hip_bfloat16 h = __float2bfloat16(f);
    union { __hip_bfloat16 h; unsigned short u; } cvt; cvt.h = h;
    return cvt.u;
}

// ---- weight prep: transpose to W[n][k] bf16 with scales folded -------------
__global__ void prep_w(const float* __restrict__ w,
                       unsigned short* __restrict__ w0t,
                       unsigned short* __restrict__ w1t) {
    int idx = blockIdx.x * 256 + threadIdx.x;   // 240*256 == 61440 exactly
    const float S000 = 1.0f / 128.0f;
    const float S011 = 1.0f / (128.0f * 1.7320508075688772f);
    const float S1X  = 1.0f / (64.0f * 1.7320508075688772f);
    const float S111 = 1.0f / (64.0f * 2.449489742783178f);
    if (idx < 320 * 128) {
        int n = idx >> 7, k = idx & 127;
        float v;
        if (n < 256) v = w[k * 256 + n] * S000;                 // w000[k][uv]
        else         v = w[32768 + k * 64 + (n - 256)] * S011;  // w011[k][uv]
        w0t[idx] = f2bf(v);
    } else {
        int i2 = idx - 320 * 128;
        int n = i2 >> 6, k = i2 & 63;
        float v;
        if (n < 128)      v = w[40960 + k * 128 + n] * S1X;           // w101
        else if (n < 256) v = w[49152 + k * 128 + (n - 128)] * S1X;   // w110
        else              v = w[57344 + k * 64  + (n - 256)] * S111;  // w111
        w1t[i2] = f2bf(v);
    }
}

// ---- x prep: f32 -> bf16 fragment layout, 32 rows/block -------------------
__global__ __launch_bounds__(256) void prep_x(const float* __restrict__ x_in,
                                              unsigned short* __restrict__ xbf) {
    __shared__ unsigned short xl[32 * 320];
    const int tid = threadIdx.x;
    const float4* src = reinterpret_cast<const float4*>(
        x_in + (size_t)blockIdx.x * 32 * 320);
    #pragma unroll
    for (int k = 0; k < 10; ++k) {
        int p = tid + (k << 8);             // [0,2560)
        float4 v = src[p];
        int row = p / 80, col = (p - row * 80) * 4;
        if (col < 128) {
            ushort4 u;
            u.x = f2bf(v.x); u.y = f2bf(v.y); u.z = f2bf(v.z); u.w = f2bf(v.w);
            *reinterpret_cast<ushort4*>(&xl[row * 320 + col]) = u;
        } else {
            float vv[4] = {v.x, v.y, v.z, v.w};
            #pragma unroll
            for (int e = 0; e < 4; ++e) {
                int f = col - 128 + e;
                int wi = f / 3, cm = f - wi * 3;
                xl[row * 320 + 128 + cm * 64 + wi] = f2bf(vv[e]);
            }
        }
    }
    __syncthreads();
    const uint4* s4 = reinterpret_cast<const uint4*>(xl);
    uint4* d4 = reinterpret_cast<uint4*>(xbf + (size_t)blockIdx.x * 32 * 320);
    #pragma unroll
    for (int k = 0; k < 5; ++k)
        d4[tid + (k << 8)] = s4[tid + (k << 8)];
}

// ---- main fused kernel -----------------------------------------------------
// 256 threads = 4 waves; batch tile = 16; wave wv owns an n-quarter.
// Swapped MFMA: D[n][batch]; lane holds n = base + grp*4 + {0..3}, batch = cn.
template <bool USE_XBF>
__global__ __launch_bounds__(256) void qhnet_main(
    const float* __restrict__ x_in,
    const unsigned short* __restrict__ xbf,
    const unsigned short* __restrict__ w0t,
    const unsigned short* __restrict__ w1t,
    float* __restrict__ out)
{
    // 51200 B: out-staging tile [8][400] float4; front 10240 B aliased for
    // x staging in the fallback path.
    __shared__ __attribute__((aligned(16))) float smemf[8 * 1600];
    float4* smemq = reinterpret_cast<float4*>(smemf);

    const int tid = threadIdx.x;
    const int b0 = blockIdx.x * 16;
    const int lane = tid & 63;
    const int wv = tid >> 6;        // wave id -> n-quarter
    const int cn = lane & 15;       // batch row in tile
    const int grp = lane >> 4;      // k-group / reg-quad select

    bf16x8 a0[4], a1[3][2];

    if (USE_XBF) {
        const unsigned short* xr = xbf + (size_t)(b0 + cn) * 320;
        #pragma unroll
        for (int ks = 0; ks < 4; ++ks)
            a0[ks] = *reinterpret_cast<const bf16x8*>(xr + ks * 32 + grp * 8);
        #pragma unroll
        for (int c = 0; c < 3; ++c)
            #pragma unroll
            for (int ks = 0; ks < 2; ++ks)
                a1[c][ks] = *reinterpret_cast<const bf16x8*>(
                    xr + 128 + c * 64 + ks * 32 + grp * 8);
    } else {
        unsigned short* x0L = reinterpret_cast<unsigned short*>(smemf); // [16][128]
        unsigned short* x1L = x0L + 16 * 128;                           // [3][16][64]
        const float4* xrow = reinterpret_cast<const float4*>(x_in + (size_t)b0 * 320);
        for (int p = tid; p < 16 * 80; p += 256) {
            int row = p / 80;
            int col = (p - row * 80) * 4;
            float4 v = xrow[p];
            int sw = (row & 7) << 3;
            if (col < 128) {
                int k = col ^ sw;
                ushort4 u;
                u.x = f2bf(v.x); u.y = f2bf(v.y); u.z = f2bf(v.z); u.w = f2bf(v.w);
                *reinterpret_cast<ushort4*>(&x0L[row * 128 + k]) = u;
            } else {
                float vv[4] = {v.x, v.y, v.z, v.w};
                #pragma unroll
                for (int e = 0; e < 4; ++e) {
                    int f = col - 128 + e;
                    int wi = f / 3, cm = f - wi * 3;
                    x1L[cm * 1024 + row * 64 + (wi ^ sw)] = f2bf(vv[e]);
                }
            }
        }
        __syncthreads();
        const int swf = (cn & 7) << 3;
        #pragma unroll
        for (int ks = 0; ks < 4; ++ks)
            a0[ks] = *reinterpret_cast<const bf16x8*>(
                &x0L[cn * 128 + ((ks * 32 + grp * 8) ^ swf)]);
        #pragma unroll
        for (int c = 0; c < 3; ++c)
            #pragma unroll
            for (int ks = 0; ks < 2; ++ks)
                a1[c][ks] = *reinterpret_cast<const bf16x8*>(
                    &x1L[c * 1024 + cn * 64 + ((ks * 32 + grp * 8) ^ swf)]);
    }

    f32x4 acc0[5] = {};
    f32x4 acc1[3][5] = {};

    const int c0base[5] = {wv * 64, wv * 64 + 16, wv * 64 + 32, wv * 64 + 48,
                           256 + wv * 16};
    const int c1base[5] = {wv * 32, wv * 32 + 16, 128 + wv * 32,
                           128 + wv * 32 + 16, 256 + wv * 16};

    // --- C0^T = W0 (A) x X0 (B), K=128 ---
    #pragma unroll
    for (int t = 0; t < 5; ++t) {
        const unsigned short* wp = w0t + (c0base[t] + cn) * 128 + grp * 8;
        #pragma unroll
        for (int ks = 0; ks < 4; ++ks) {
            bf16x8 b = *reinterpret_cast<const bf16x8*>(wp + ks * 32);
            acc0[t] = __builtin_amdgcn_mfma_f32_16x16x32_bf16(b, a0[ks], acc0[t], 0, 0, 0);
        }
    }
    // --- C1k^T, K=64, weight frag shared across the 3 components ---
    #pragma unroll
    for (int t = 0; t < 5; ++t) {
        const unsigned short* wp = w1t + (c1base[t] + cn) * 64 + grp * 8;
        #pragma unroll
        for (int ks = 0; ks < 2; ++ks) {
            bf16x8 b = *reinterpret_cast<const bf16x8*>(wp + ks * 32);
            #pragma unroll
            for (int c = 0; c < 3; ++c)
                acc1[c][t] = __builtin_amdgcn_mfma_f32_16x16x32_bf16(b, a1[c][ks], acc1[c][t], 0, 0, 0);
        }
    }

    // --- epilogue: 2 phases x 8 rows; quad scatter -> coalesced copy ---
    const int g2 = grp >> 1, g1 = grp & 1;
    const int tr = cn & 7;              // smem tile row when active
    float4* rowq = smemq + tr * 400;    // XOR key = tr (bijective, 8-group)

    #pragma unroll
    for (int h = 0; h < 2; ++h) {
        if (!USE_XBF || h) __syncthreads();   // protect LDS alias / prev copy
        if ((cn >> 3) == h) {
            #pragma unroll
            for (int t = 0; t < 4; ++t) {               // blk00
                int q = (wv * 4 + t) * 10 + grp;
                rowq[q ^ tr] = *reinterpret_cast<const float4*>(&acc0[t]);
            }
            #pragma unroll
            for (int t = 0; t < 2; ++t) {               // blk01: 3 quads
                int u01 = 4 * wv + 2 * t + g2;
                int q0 = u01 * 10 + 4 + 3 * g1;
                float4 qa = {acc1[0][t][0], acc1[1][t][0], acc1[2][t][0], acc1[0][t][1]};
                float4 qb = {acc1[1][t][1], acc1[2][t][1], acc1[0][t][2], acc1[1][t][2]};
                float4 qc = {acc1[2][t][2], acc1[0][t][3], acc1[1][t][3], acc1[2][t][3]};
                rowq[q0 ^ tr]       = qa;
                rowq[(q0 + 1) ^ tr] = qb;
                rowq[(q0 + 2) ^ tr] = qc;
            }
            #pragma unroll
            for (int t = 0; t < 2; ++t) {               // blk10
                int rr = 16 + 3 * (2 * wv + t);
                #pragma unroll
                for (int c = 0; c < 3; ++c) {
                    int q = (rr + c) * 10 + grp;
                    rowq[q ^ tr] = *reinterpret_cast<const float4*>(&acc1[c][t + 2]);
                }
            }
            {                                           // blk11: 9 quads
                int rr = 16 + 3 * (2 * wv + g2);
                int cq = 4 + 3 * g1;
                f32x4 d = acc0[4];
                f32x4 t0 = acc1[0][4], t1 = acc1[1][4], t2 = acc1[2][4];
                float4 q00 = {d[0], t2[0], -t1[0], d[1]};
                float4 q01 = {t2[1], -t1[1], d[2], t2[2]};
                float4 q02 = {-t1[2], d[3], t2[3], -t1[3]};
                float4 q10 = {-t2[0], d[0], t0[0], -t2[1]};
                float4 q11 = {d[1], t0[1], -t2[2], d[2]};
                float4 q12 = {t0[2], -t2[3], d[3], t0[3]};
                float4 q20 = {t1[0], -t0[0], d[0], t1[1]};
                float4 q21 = {-t0[1], d[1], t1[2], -t0[2]};
                float4 q22 = {d[2], t1[3], -t0[3], d[3]};
                rowq[(rr * 10 + cq)            ^ tr] = q00;
                rowq[(rr * 10 + cq + 1)        ^ tr] = q01;
                rowq[(rr * 10 + cq + 2)        ^ tr] = q02;
                rowq[((rr + 1) * 10 + cq)      ^ tr] = q10;
                rowq[((rr + 1) * 10 + cq + 1)  ^ tr] = q11;
                rowq[((rr + 1) * 10 + cq + 2)  ^ tr] = q12;
                rowq[((rr + 2) * 10 + cq)      ^ tr] = q20;
                rowq[((rr + 2) * 10 + cq + 1)  ^ tr] = q21;
                rowq[((rr + 2) * 10 + cq + 2)  ^ tr] = q22;
            }
        }
        __syncthreads();
        // coalesced copy-out: 8 rows = 3200 quads, 256 threads x 12.5
        float* dstf = out + (size_t)(b0 + h * 8) * 1600;
        #pragma unroll
        for (int k = 0; k < 13; ++k) {
            int p = tid + (k << 8);
            if (k < 12 || tid < 128) {
                int row = p / 400;
                int q = p - row * 400;
                *reinterpret_cast<float4*>(dstf + (size_t)p * 4) =
                    smemq[row * 400 + (q ^ row)];
            }
        }
    }
}

extern "C" void kernel_launch(void* const* d_in, const int* in_sizes, int n_in,
                              void* d_out, int out_size, void* d_ws, size_t ws_size,
                              hipStream_t stream) {
    const float* x_in = (const float*)d_in[0];
    const float* weights = (const float*)d_in[1];
    float* out = (float*)d_out;
    unsigned short* w0t = (unsigned short*)d_ws;            // 320*128 bf16
    unsigned short* w1t = w0t + 320 * 128;                  // 320*64  bf16
    unsigned short* xbf = w1t + 320 * 64;                   // B*320   bf16
    int B = in_sizes[0] / 320;                              // 100000

    prep_w<<<240, 256, 0, stream>>>(weights, w0t, w1t);

    size_t need = ((size_t)320 * 192 + (size_t)B * 320) * sizeof(unsigned short);
    if (ws_size >= need && (B % 32) == 0) {
        prep_x<<<B / 32, 256, 0, stream>>>(x_in, xbf);
        qhnet_main<true><<<B / 16, 256, 0, stream>>>(x_in, xbf, w0t, w1t, out);
    } else {
        qhnet_main<false><<<B / 16, 256, 0, stream>>>(x_in, xbf, w0t, w1t, out);
    }
}

// Round 6
// 247.945 us; speedup vs baseline: 1.2066x; 1.0670x over previous
//
#include <hip/hip_runtime.h>
#include <hip/hip_bf16.h>

// QHNet block-linear layer. R6: R2/R5 structure (in-kernel x->LDS staging,
// swapped-operand MFMA, quad LDS out-scatter, coalesced copy-out) but ALL
// barriers are hand-rolled `s_waitcnt lgkmcnt(0); s_barrier` instead of
// __syncthreads(). __syncthreads drains vmcnt(0) (m97 barrier-drain), which
// forced each block to wait for its own HBM stores to retire twice per
// block at only 3 blocks/CU -- the common limiter of R2/R4/R5 (~225us
// plateau). No barrier here needs vmcnt: they only order LDS ops.

typedef short bf16x8 __attribute__((ext_vector_type(8)));
typedef float f32x4 __attribute__((ext_vector_type(4)));

// LDS-only barrier: wait own LDS ops, rendezvous; global stores stay in flight.
#define LGKM_BARRIER()                                         \
    do {                                                       \
        asm volatile("s_waitcnt lgkmcnt(0)" ::: "memory");     \
        __builtin_amdgcn_sched_barrier(0);                     \
        __builtin_amdgcn_s_barrier();                          \
        __builtin_amdgcn_sched_barrier(0);                     \
    } while (0)

static __device__ __forceinline__ unsigned short f2bf(float f) {
    __hip_bfloat16 h = __float2bfloat16(f);
    union { __hip_bfloat16 h; unsigned short u; } cvt; cvt.h = h;
    return cvt.u;
}

// ---- weight prep: transpose to W[n][k] bf16 with scales folded -------------
__global__ void prep_w(const float* __restrict__ w,
                       unsigned short* __restrict__ w0t,
                       unsigned short* __restrict__ w1t) {
    int idx = blockIdx.x * 256 + threadIdx.x;   // 240*256 == 61440 exactly
    const float S000 = 1.0f / 128.0f;
    const float S011 = 1.0f / (128.0f * 1.7320508075688772f);
    const float S1X  = 1.0f / (64.0f * 1.7320508075688772f);
    const float S111 = 1.0f / (64.0f * 2.449489742783178f);
    if (idx < 320 * 128) {
        int n = idx >> 7, k = idx & 127;
        float v;
        if (n < 256) v = w[k * 256 + n] * S000;                 // w000[k][uv]
        else         v = w[32768 + k * 64 + (n - 256)] * S011;  // w011[k][uv]
        w0t[idx] = f2bf(v);
    } else {
        int i2 = idx - 320 * 128;
        int n = i2 >> 6, k = i2 & 63;
        float v;
        if (n < 128)      v = w[40960 + k * 128 + n] * S1X;           // w101
        else if (n < 256) v = w[49152 + k * 128 + (n - 128)] * S1X;   // w110
        else              v = w[57344 + k * 64  + (n - 256)] * S111;  // w111
        w1t[i2] = f2bf(v);
    }
}

// ---- main fused kernel -----------------------------------------------------
// 256 threads = 4 waves; batch tile = 16; wave wv owns an n-quarter.
// Swapped MFMA: D[n][batch]; lane holds n = base + grp*4 + {0..3}, batch = cn.
__global__ __launch_bounds__(256) void qhnet_main(
    const float* __restrict__ x_in,
    const unsigned short* __restrict__ w0t,
    const unsigned short* __restrict__ w1t,
    float* __restrict__ out)
{
    // 51200 B: out-staging tile [8][400] float4; front 10240 B aliased as
    // bf16 x-staging until the (barrier-protected) fragment reads complete.
    __shared__ __attribute__((aligned(16))) float smemf[8 * 1600];
    float4* smemq = reinterpret_cast<float4*>(smemf);
    unsigned short* x0L = reinterpret_cast<unsigned short*>(smemf); // [16][128]
    unsigned short* x1L = x0L + 16 * 128;                           // [3][16][64]

    const int tid = threadIdx.x;
    const int b0 = blockIdx.x * 16;

    // --- stage x tile -> LDS as bf16 (coalesced float4 reads) ---
    const float4* xrow = reinterpret_cast<const float4*>(x_in + (size_t)b0 * 320);
    #pragma unroll
    for (int k = 0; k < 5; ++k) {
        int p = tid + (k << 8);             // 1280 = 5*256 exactly
        float4 v = xrow[p];
        int row = p / 80;
        int col = (p - row * 80) * 4;
        int sw = (row & 7) << 3;
        if (col < 128) {
            int kk = col ^ sw;              // XOR-swizzle keeps 4-aligned runs
            ushort4 u;
            u.x = f2bf(v.x); u.y = f2bf(v.y); u.z = f2bf(v.z); u.w = f2bf(v.w);
            *reinterpret_cast<ushort4*>(&x0L[row * 128 + kk]) = u;
        } else {
            float vv[4] = {v.x, v.y, v.z, v.w};
            #pragma unroll
            for (int e = 0; e < 4; ++e) {
                int f = col - 128 + e;
                int wi = f / 3, cm = f - wi * 3;
                x1L[cm * 1024 + row * 64 + (wi ^ sw)] = f2bf(vv[e]);
            }
        }
    }
    LGKM_BARRIER();                         // staging visible to all waves

    const int lane = tid & 63;
    const int wv = tid >> 6;        // wave id -> n-quarter
    const int cn = lane & 15;       // batch row in tile
    const int grp = lane >> 4;      // k-group / reg-quad select
    const int swf = (cn & 7) << 3;

    // --- x fragments from LDS ---
    bf16x8 a0[4], a1[3][2];
    #pragma unroll
    for (int ks = 0; ks < 4; ++ks)
        a0[ks] = *reinterpret_cast<const bf16x8*>(
            &x0L[cn * 128 + ((ks * 32 + grp * 8) ^ swf)]);
    #pragma unroll
    for (int c = 0; c < 3; ++c)
        #pragma unroll
        for (int ks = 0; ks < 2; ++ks)
            a1[c][ks] = *reinterpret_cast<const bf16x8*>(
                &x1L[c * 1024 + cn * 64 + ((ks * 32 + grp * 8) ^ swf)]);
    LGKM_BARRIER();                 // all waves' frag reads done ->
                                    // safe to overwrite aliased LDS later

    f32x4 acc0[5] = {};
    f32x4 acc1[3][5] = {};

    const int c0base[5] = {wv * 64, wv * 64 + 16, wv * 64 + 32, wv * 64 + 48,
                           256 + wv * 16};
    const int c1base[5] = {wv * 32, wv * 32 + 16, 128 + wv * 32,
                           128 + wv * 32 + 16, 256 + wv * 16};

    // --- C0^T = W0 (A) x X0 (B), K=128 ---
    #pragma unroll
    for (int t = 0; t < 5; ++t) {
        const unsigned short* wp = w0t + (c0base[t] + cn) * 128 + grp * 8;
        #pragma unroll
        for (int ks = 0; ks < 4; ++ks) {
            bf16x8 b = *reinterpret_cast<const bf16x8*>(wp + ks * 32);
            acc0[t] = __builtin_amdgcn_mfma_f32_16x16x32_bf16(b, a0[ks], acc0[t], 0, 0, 0);
        }
    }
    // --- C1k^T, K=64, weight frag shared across the 3 components ---
    #pragma unroll
    for (int t = 0; t < 5; ++t) {
        const unsigned short* wp = w1t + (c1base[t] + cn) * 64 + grp * 8;
        #pragma unroll
        for (int ks = 0; ks < 2; ++ks) {
            bf16x8 b = *reinterpret_cast<const bf16x8*>(wp + ks * 32);
            #pragma unroll
            for (int c = 0; c < 3; ++c)
                acc1[c][t] = __builtin_amdgcn_mfma_f32_16x16x32_bf16(b, a1[c][ks], acc1[c][t], 0, 0, 0);
        }
    }

    // --- epilogue: 2 phases x 8 rows; quad scatter -> coalesced copy ---
    const int g2 = grp >> 1, g1 = grp & 1;
    const int tr = cn & 7;              // smem tile row when active
    float4* rowq = smemq + tr * 400;    // XOR key = tr (bijective in 8-group)

    #pragma unroll
    for (int h = 0; h < 2; ++h) {
        if (h) LGKM_BARRIER();          // prev copy-out LDS reads done
        if ((cn >> 3) == h) {
            #pragma unroll
            for (int t = 0; t < 4; ++t) {               // blk00
                int q = (wv * 4 + t) * 10 + grp;
                rowq[q ^ tr] = *reinterpret_cast<const float4*>(&acc0[t]);
            }
            #pragma unroll
            for (int t = 0; t < 2; ++t) {               // blk01: 3 quads
                int u01 = 4 * wv + 2 * t + g2;
                int q0 = u01 * 10 + 4 + 3 * g1;
                float4 qa = {acc1[0][t][0], acc1[1][t][0], acc1[2][t][0], acc1[0][t][1]};
                float4 qb = {acc1[1][t][1], acc1[2][t][1], acc1[0][t][2], acc1[1][t][2]};
                float4 qc = {acc1[2][t][2], acc1[0][t][3], acc1[1][t][3], acc1[2][t][3]};
                rowq[q0 ^ tr]       = qa;
                rowq[(q0 + 1) ^ tr] = qb;
                rowq[(q0 + 2) ^ tr] = qc;
            }
            #pragma unroll
            for (int t = 0; t < 2; ++t) {               // blk10
                int rr = 16 + 3 * (2 * wv + t);
                #pragma unroll
                for (int c = 0; c < 3; ++c) {
                    int q = (rr + c) * 10 + grp;
                    rowq[q ^ tr] = *reinterpret_cast<const float4*>(&acc1[c][t + 2]);
                }
            }
            {                                           // blk11: 9 quads
                int rr = 16 + 3 * (2 * wv + g2);
                int cq = 4 + 3 * g1;
                f32x4 d = acc0[4];
                f32x4 t0 = acc1[0][4], t1 = acc1[1][4], t2 = acc1[2][4];
                float4 q00 = {d[0], t2[0], -t1[0], d[1]};
                float4 q01 = {t2[1], -t1[1], d[2], t2[2]};
                float4 q02 = {-t1[2], d[3], t2[3], -t1[3]};
                float4 q10 = {-t2[0], d[0], t0[0], -t2[1]};
                float4 q11 = {d[1], t0[1], -t2[2], d[2]};
                float4 q12 = {t0[2], -t2[3], d[3], t0[3]};
                float4 q20 = {t1[0], -t0[0], d[0], t1[1]};
                float4 q21 = {-t0[1], d[1], t1[2], -t0[2]};
                float4 q22 = {d[2], t1[3], -t0[3], d[3]};
                rowq[(rr * 10 + cq)            ^ tr] = q00;
                rowq[(rr * 10 + cq + 1)        ^ tr] = q01;
                rowq[(rr * 10 + cq + 2)        ^ tr] = q02;
                rowq[((rr + 1) * 10 + cq)      ^ tr] = q10;
                rowq[((rr + 1) * 10 + cq + 1)  ^ tr] = q11;
                rowq[((rr + 1) * 10 + cq + 2)  ^ tr] = q12;
                rowq[((rr + 2) * 10 + cq)      ^ tr] = q20;
                rowq[((rr + 2) * 10 + cq + 1)  ^ tr] = q21;
                rowq[((rr + 2) * 10 + cq + 2)  ^ tr] = q22;
            }
        }
        LGKM_BARRIER();                 // scatter ds_writes visible
        // coalesced copy-out: 8 rows = 3200 quads, 256 threads x 12.5
        float* dstf = out + (size_t)(b0 + h * 8) * 1600;
        #pragma unroll
        for (int k = 0; k < 13; ++k) {
            int p = tid + (k << 8);
            if (k < 12 || tid < 128) {
                int row = p / 400;
                int q = p - row * 400;
                *reinterpret_cast<float4*>(dstf + (size_t)p * 4) =
                    smemq[row * 400 + (q ^ row)];
            }
        }
    }
    // kernel end: implicit store drain; no trailing barrier needed
}

extern "C" void kernel_launch(void* const* d_in, const int* in_sizes, int n_in,
                              void* d_out, int out_size, void* d_ws, size_t ws_size,
                              hipStream_t stream) {
    const float* x_in = (const float*)d_in[0];
    const float* weights = (const float*)d_in[1];
    float* out = (float*)d_out;
    unsigned short* w0t = (unsigned short*)d_ws;            // 320*128 bf16
    unsigned short* w1t = w0t + 320 * 128;                  // 320*64  bf16
    int B = in_sizes[0] / 320;                              // 100000

    prep_w<<<240, 256, 0, stream>>>(weights, w0t, w1t);
    qhnet_main<<<B / 16, 256, 0, stream>>>(x_in, w0t, w1t, out);
}

// Round 8
// 236.705 us; speedup vs baseline: 1.2640x; 1.0475x over previous
//
#include <hip/hip_runtime.h>
#include <hip/hip_bf16.h>

// QHNet block-linear layer. R7 == R6 structure (in-kernel x->LDS staging,
// swapped-operand MFMA, quad LDS out-scatter, LGKM-only barriers, coalesced
// copy-out) with ONE change: non-temporal output stores + non-temporal x
// loads. Diagnostic for the 224us plateau == (2*WRITE+READ)/6.3TB/s == 223us
// coincidence: if store-miss allocate/MALL streaming doubles write-side HBM
// traffic, nt stores (no allocate-fetch, evict-first) reclaim it.
// (compile fix: nt builtins need ext_vector types, not HIP_vector_type)

typedef short bf16x8 __attribute__((ext_vector_type(8)));
typedef float f32x4 __attribute__((ext_vector_type(4)));

// LDS-only barrier: wait own LDS ops, rendezvous; global stores stay in flight.
#define LGKM_BARRIER()                                         \
    do {                                                       \
        asm volatile("s_waitcnt lgkmcnt(0)" ::: "memory");     \
        __builtin_amdgcn_sched_barrier(0);                     \
        __builtin_amdgcn_s_barrier();                          \
        __builtin_amdgcn_sched_barrier(0);                     \
    } while (0)

static __device__ __forceinline__ unsigned short f2bf(float f) {
    __hip_bfloat16 h = __float2bfloat16(f);
    union { __hip_bfloat16 h; unsigned short u; } cvt; cvt.h = h;
    return cvt.u;
}

// ---- weight prep: transpose to W[n][k] bf16 with scales folded -------------
__global__ void prep_w(const float* __restrict__ w,
                       unsigned short* __restrict__ w0t,
                       unsigned short* __restrict__ w1t) {
    int idx = blockIdx.x * 256 + threadIdx.x;   // 240*256 == 61440 exactly
    const float S000 = 1.0f / 128.0f;
    const float S011 = 1.0f / (128.0f * 1.7320508075688772f);
    const float S1X  = 1.0f / (64.0f * 1.7320508075688772f);
    const float S111 = 1.0f / (64.0f * 2.449489742783178f);
    if (idx < 320 * 128) {
        int n = idx >> 7, k = idx & 127;
        float v;
        if (n < 256) v = w[k * 256 + n] * S000;                 // w000[k][uv]
        else         v = w[32768 + k * 64 + (n - 256)] * S011;  // w011[k][uv]
        w0t[idx] = f2bf(v);
    } else {
        int i2 = idx - 320 * 128;
        int n = i2 >> 6, k = i2 & 63;
        float v;
        if (n < 128)      v = w[40960 + k * 128 + n] * S1X;           // w101
        else if (n < 256) v = w[49152 + k * 128 + (n - 128)] * S1X;   // w110
        else              v = w[57344 + k * 64  + (n - 256)] * S111;  // w111
        w1t[i2] = f2bf(v);
    }
}

// ---- main fused kernel -----------------------------------------------------
// 256 threads = 4 waves; batch tile = 16; wave wv owns an n-quarter.
// Swapped MFMA: D[n][batch]; lane holds n = base + grp*4 + {0..3}, batch = cn.
__global__ __launch_bounds__(256) void qhnet_main(
    const float* __restrict__ x_in,
    const unsigned short* __restrict__ w0t,
    const unsigned short* __restrict__ w1t,
    float* __restrict__ out)
{
    // 51200 B: out-staging tile [8][400] float4; front 10240 B aliased as
    // bf16 x-staging until the (barrier-protected) fragment reads complete.
    __shared__ __attribute__((aligned(16))) float smemf[8 * 1600];
    f32x4* smemq = reinterpret_cast<f32x4*>(smemf);
    unsigned short* x0L = reinterpret_cast<unsigned short*>(smemf); // [16][128]
    unsigned short* x1L = x0L + 16 * 128;                           // [3][16][64]

    const int tid = threadIdx.x;
    const int b0 = blockIdx.x * 16;

    // --- stage x tile -> LDS as bf16 (nt float4 loads: read-once stream) ---
    const f32x4* xrow = reinterpret_cast<const f32x4*>(x_in + (size_t)b0 * 320);
    #pragma unroll
    for (int k = 0; k < 5; ++k) {
        int p = tid + (k << 8);             // 1280 = 5*256 exactly
        f32x4 v = __builtin_nontemporal_load(&xrow[p]);
        int row = p / 80;
        int col = (p - row * 80) * 4;
        int sw = (row & 7) << 3;
        if (col < 128) {
            int kk = col ^ sw;              // XOR-swizzle keeps 4-aligned runs
            ushort4 u;
            u.x = f2bf(v[0]); u.y = f2bf(v[1]); u.z = f2bf(v[2]); u.w = f2bf(v[3]);
            *reinterpret_cast<ushort4*>(&x0L[row * 128 + kk]) = u;
        } else {
            #pragma unroll
            for (int e = 0; e < 4; ++e) {
                int f = col - 128 + e;
                int wi = f / 3, cm = f - wi * 3;
                x1L[cm * 1024 + row * 64 + (wi ^ sw)] = f2bf(v[e]);
            }
        }
    }
    LGKM_BARRIER();                         // staging visible to all waves

    const int lane = tid & 63;
    const int wv = tid >> 6;        // wave id -> n-quarter
    const int cn = lane & 15;       // batch row in tile
    const int grp = lane >> 4;      // k-group / reg-quad select
    const int swf = (cn & 7) << 3;

    // --- x fragments from LDS ---
    bf16x8 a0[4], a1[3][2];
    #pragma unroll
    for (int ks = 0; ks < 4; ++ks)
        a0[ks] = *reinterpret_cast<const bf16x8*>(
            &x0L[cn * 128 + ((ks * 32 + grp * 8) ^ swf)]);
    #pragma unroll
    for (int c = 0; c < 3; ++c)
        #pragma unroll
        for (int ks = 0; ks < 2; ++ks)
            a1[c][ks] = *reinterpret_cast<const bf16x8*>(
                &x1L[c * 1024 + cn * 64 + ((ks * 32 + grp * 8) ^ swf)]);
    LGKM_BARRIER();                 // all waves' frag reads done ->
                                    // safe to overwrite aliased LDS later

    f32x4 acc0[5] = {};
    f32x4 acc1[3][5] = {};

    const int c0base[5] = {wv * 64, wv * 64 + 16, wv * 64 + 32, wv * 64 + 48,
                           256 + wv * 16};
    const int c1base[5] = {wv * 32, wv * 32 + 16, 128 + wv * 32,
                           128 + wv * 32 + 16, 256 + wv * 16};

    // --- C0^T = W0 (A) x X0 (B), K=128 ---
    #pragma unroll
    for (int t = 0; t < 5; ++t) {
        const unsigned short* wp = w0t + (c0base[t] + cn) * 128 + grp * 8;
        #pragma unroll
        for (int ks = 0; ks < 4; ++ks) {
            bf16x8 b = *reinterpret_cast<const bf16x8*>(wp + ks * 32);
            acc0[t] = __builtin_amdgcn_mfma_f32_16x16x32_bf16(b, a0[ks], acc0[t], 0, 0, 0);
        }
    }
    // --- C1k^T, K=64, weight frag shared across the 3 components ---
    #pragma unroll
    for (int t = 0; t < 5; ++t) {
        const unsigned short* wp = w1t + (c1base[t] + cn) * 64 + grp * 8;
        #pragma unroll
        for (int ks = 0; ks < 2; ++ks) {
            bf16x8 b = *reinterpret_cast<const bf16x8*>(wp + ks * 32);
            #pragma unroll
            for (int c = 0; c < 3; ++c)
                acc1[c][t] = __builtin_amdgcn_mfma_f32_16x16x32_bf16(b, a1[c][ks], acc1[c][t], 0, 0, 0);
        }
    }

    // --- epilogue: 2 phases x 8 rows; quad scatter -> coalesced nt copy ---
    const int g2 = grp >> 1, g1 = grp & 1;
    const int tr = cn & 7;              // smem tile row when active
    f32x4* rowq = smemq + tr * 400;     // XOR key = tr (bijective in 8-group)

    #pragma unroll
    for (int h = 0; h < 2; ++h) {
        if (h) LGKM_BARRIER();          // prev copy-out LDS reads done
        if ((cn >> 3) == h) {
            #pragma unroll
            for (int t = 0; t < 4; ++t) {               // blk00
                int q = (wv * 4 + t) * 10 + grp;
                rowq[q ^ tr] = acc0[t];
            }
            #pragma unroll
            for (int t = 0; t < 2; ++t) {               // blk01: 3 quads
                int u01 = 4 * wv + 2 * t + g2;
                int q0 = u01 * 10 + 4 + 3 * g1;
                f32x4 qa = {acc1[0][t][0], acc1[1][t][0], acc1[2][t][0], acc1[0][t][1]};
                f32x4 qb = {acc1[1][t][1], acc1[2][t][1], acc1[0][t][2], acc1[1][t][2]};
                f32x4 qc = {acc1[2][t][2], acc1[0][t][3], acc1[1][t][3], acc1[2][t][3]};
                rowq[q0 ^ tr]       = qa;
                rowq[(q0 + 1) ^ tr] = qb;
                rowq[(q0 + 2) ^ tr] = qc;
            }
            #pragma unroll
            for (int t = 0; t < 2; ++t) {               // blk10
                int rr = 16 + 3 * (2 * wv + t);
                #pragma unroll
                for (int c = 0; c < 3; ++c) {
                    int q = (rr + c) * 10 + grp;
                    rowq[q ^ tr] = acc1[c][t + 2];
                }
            }
            {                                           // blk11: 9 quads
                int rr = 16 + 3 * (2 * wv + g2);
                int cq = 4 + 3 * g1;
                f32x4 d = acc0[4];
                f32x4 t0 = acc1[0][4], t1 = acc1[1][4], t2 = acc1[2][4];
                f32x4 q00 = {d[0], t2[0], -t1[0], d[1]};
                f32x4 q01 = {t2[1], -t1[1], d[2], t2[2]};
                f32x4 q02 = {-t1[2], d[3], t2[3], -t1[3]};
                f32x4 q10 = {-t2[0], d[0], t0[0], -t2[1]};
                f32x4 q11 = {d[1], t0[1], -t2[2], d[2]};
                f32x4 q12 = {t0[2], -t2[3], d[3], t0[3]};
                f32x4 q20 = {t1[0], -t0[0], d[0], t1[1]};
                f32x4 q21 = {-t0[1], d[1], t1[2], -t0[2]};
                f32x4 q22 = {d[2], t1[3], -t0[3], d[3]};
                rowq[(rr * 10 + cq)            ^ tr] = q00;
                rowq[(rr * 10 + cq + 1)        ^ tr] = q01;
                rowq[(rr * 10 + cq + 2)        ^ tr] = q02;
                rowq[((rr + 1) * 10 + cq)      ^ tr] = q10;
                rowq[((rr + 1) * 10 + cq + 1)  ^ tr] = q11;
                rowq[((rr + 1) * 10 + cq + 2)  ^ tr] = q12;
                rowq[((rr + 2) * 10 + cq)      ^ tr] = q20;
                rowq[((rr + 2) * 10 + cq + 1)  ^ tr] = q21;
                rowq[((rr + 2) * 10 + cq + 2)  ^ tr] = q22;
            }
        }
        LGKM_BARRIER();                 // scatter ds_writes visible
        // coalesced nt copy-out: 8 rows = 3200 quads, 256 threads x 12.5
        float* dstf = out + (size_t)(b0 + h * 8) * 1600;
        #pragma unroll
        for (int k = 0; k < 13; ++k) {
            int p = tid + (k << 8);
            if (k < 12 || tid < 128) {
                int row = p / 400;
                int q = p - row * 400;
                f32x4 val = smemq[row * 400 + (q ^ row)];
                __builtin_nontemporal_store(
                    val, reinterpret_cast<f32x4*>(dstf + (size_t)p * 4));
            }
        }
    }
    // kernel end: implicit store drain; no trailing barrier needed
}

extern "C" void kernel_launch(void* const* d_in, const int* in_sizes, int n_in,
                              void* d_out, int out_size, void* d_ws, size_t ws_size,
                              hipStream_t stream) {
    const float* x_in = (const float*)d_in[0];
    const float* weights = (const float*)d_in[1];
    float* out = (float*)d_out;
    unsigned short* w0t = (unsigned short*)d_ws;            // 320*128 bf16
    unsigned short* w1t = w0t + 320 * 128;                  // 320*64  bf16
    int B = in_sizes[0] / 320;                              // 100000

    prep_w<<<240, 256, 0, stream>>>(weights, w0t, w1t);
    qhnet_main<<<B / 16, 256, 0, stream>>>(x_in, w0t, w1t, out);
}